// Round 1
// baseline (108.676 us; speedup 1.0000x reference)
//
#include <hip/hip_runtime.h>
#include <hip/hip_bf16.h>

// LGCN on MI355X. N=1600, Fin=1433, GCN hidden=32, two LGConv blocks (+8 ch each),
// out 7 channels, row mask. adj is dense binary [1600,1600], avg degree ~16.

constexpr int NN   = 1600;
constexpr int FIN  = 1433;
constexpr int HGCN = 32;
constexpr int HE   = 48;    // h_ext row stride (32 + 8 + 8)
constexpr int NBS  = 96;    // CSR neighbor stride (deg ~ Binomial(1600,0.01), max << 96)
constexpr float BN_EPS = 1e-3f;

// ---------------- mask layout detection (bool could be int32 / uint8 / f32) ----
__global__ void detect_mask_k(const unsigned char* __restrict__ mb, int* __restrict__ flag) {
    int lane = threadIdx.x;
    bool odd = false, flt = false;
    for (int i = lane; i < NN; i += 64) {       // first 1600 bytes: safe in all layouts
        unsigned char b = mb[i];
        if (b) {
            int r = i & 3;
            if (r != 0) odd = true;
            if (r >= 2 && (b == 0x3F || b == 0x80)) flt = true;   // 1.0f = 00 00 80 3F
        }
    }
    unsigned long long mo = __ballot(odd);
    unsigned long long mf = __ballot(flt);
    if (lane == 0) *flag = mf ? 2 : (mo ? 1 : 0);  // 2=f32, 1=u8, 0=i32
}

// ---------------- CSR build: ordered, deterministic ballot compaction ----------
__global__ void build_csr_k(const float* __restrict__ adj, int* __restrict__ deg,
                            unsigned short* __restrict__ nbr) {
    int row  = blockIdx.x;
    int lane = threadIdx.x;                      // block = 64 (one wave)
    const float* ar = adj + (size_t)row * NN;
    unsigned short* nb = nbr + (size_t)row * NBS;
    int cnt = 0;
    for (int base = 0; base < NN; base += 64) {  // 1600 % 64 == 0
        float v = ar[base + lane];
        bool p = (v != 0.0f);
        unsigned long long m = __ballot(p);
        if (p) {
            int off = cnt + __popcll(m & ((1ull << lane) - 1ull));
            if (off < NBS) nb[off] = (unsigned short)(base + lane);
        }
        cnt += __popcll(m);
    }
    if (lane == 0) deg[row] = cnt < NBS ? cnt : NBS;
}

// ---------------- h0 = x @ W0   [1600,1433]@[1433,32] ---------------------------
__global__ void gemm_xw0_k(const float* __restrict__ x, const float* __restrict__ W0,
                           float* __restrict__ h0) {
    int row = blockIdx.x;
    int t   = threadIdx.x;                       // block = 256
    int n   = t & 31;
    int kc  = t >> 5;                            // 0..7 k-chunks
    const float* xr = x + (size_t)row * FIN;
    float acc = 0.f;
    for (int k = kc; k < FIN; k += 8)
        acc += xr[k] * W0[k * HGCN + n];
    __shared__ float red[256];
    red[t] = acc;
    __syncthreads();
    if (t < 32) {
        float s = 0.f;
        #pragma unroll
        for (int c = 0; c < 8; ++c) s += red[c * 32 + t];
        h0[row * HGCN + t] = s;
    }
}

// ---------------- h_ext[:,0:32] = adj @ h0 (CSR, adj values are exactly 1.0) ----
__global__ void spmv32_k(const int* __restrict__ deg, const unsigned short* __restrict__ nbr,
                         const float* __restrict__ h0, float* __restrict__ he) {
    int row = blockIdx.x;
    int f   = threadIdx.x;                       // block = 64, lanes 0..31 active
    if (f >= HGCN) return;
    int d = deg[row];
    const unsigned short* nb = nbr + (size_t)row * NBS;
    float acc = 0.f;
    for (int it = 0; it < d; ++it)
        acc += h0[(int)nb[it] * HGCN + f];
    he[row * HE + f] = acc;
}

// ---------------- fused topk(K=8) + conv1d(5) + conv1d(5) + BN ------------------
// top_k over adj[i,:]*h[:,f]: the non-neighbor entries are exact 0.0, so result =
// up to 8 largest POSITIVE neighbor values (desc), zero-padded. Branchless bubble.
template<int F, int MID>
__global__ void lgconv_k(const int* __restrict__ deg, const unsigned short* __restrict__ nbr,
                         const float* __restrict__ Wa, const float* __restrict__ Wb,
                         const float* __restrict__ g,  const float* __restrict__ bb,
                         const float* __restrict__ mm, const float* __restrict__ vv,
                         float* __restrict__ he) {
    __shared__ float T[9][F];
    __shared__ float C1[5][MID];
    __shared__ float sWa[5 * F * MID];
    int row  = blockIdx.x;
    int lane = threadIdx.x;                      // block = 64 (one wave)

    for (int i = lane; i < 5 * F * MID; i += 64) sWa[i] = Wa[i];

    int d = deg[row];
    const unsigned short* nb = nbr + (size_t)row * NBS;

    if (lane < F) {
        float t0=0.f,t1=0.f,t2=0.f,t3=0.f,t4=0.f,t5=0.f,t6=0.f,t7=0.f;
        for (int it = 0; it < d; ++it) {
            float val = he[(int)nb[it] * HE + lane];
            float c;
            c = t0; t0 = fmaxf(c, val); val = fminf(c, val);
            c = t1; t1 = fmaxf(c, val); val = fminf(c, val);
            c = t2; t2 = fmaxf(c, val); val = fminf(c, val);
            c = t3; t3 = fmaxf(c, val); val = fminf(c, val);
            c = t4; t4 = fmaxf(c, val); val = fminf(c, val);
            c = t5; t5 = fmaxf(c, val); val = fminf(c, val);
            c = t6; t6 = fmaxf(c, val); val = fminf(c, val);
            c = t7; t7 = fmaxf(c, val); val = fminf(c, val);
        }
        T[0][lane] = he[row * HE + lane];        // own feature first
        T[1][lane] = t0; T[2][lane] = t1; T[3][lane] = t2; T[4][lane] = t3;
        T[5][lane] = t4; T[6][lane] = t5; T[7][lane] = t6; T[8][lane] = t7;
    }
    __syncthreads();

    // conv1: out[p,o] = sum_{kw,ci} T[p+kw][ci] * Wa[kw,ci,o]   (5*MID outputs)
    for (int oi = lane; oi < 5 * MID; oi += 64) {
        int p = oi / MID, o = oi - p * MID;
        float acc = 0.f;
        #pragma unroll
        for (int kw = 0; kw < 5; ++kw) {
            const float* w  = &sWa[kw * F * MID + o];
            const float* tt = &T[p + kw][0];
            for (int ci = 0; ci < F; ++ci)
                acc += tt[ci] * w[ci * MID];
        }
        C1[p][o] = acc;
    }
    __syncthreads();

    // conv2 (only output position 0 survives VALID) + batchnorm
    if (lane < 8) {
        float acc = 0.f;
        #pragma unroll
        for (int kw = 0; kw < 5; ++kw)
            for (int ci = 0; ci < MID; ++ci)
                acc += C1[kw][ci] * Wb[(kw * MID + ci) * 8 + lane];
        float y = g[lane] * (acc - mm[lane]) * rsqrtf(vv[lane] + BN_EPS) + bb[lane];
        he[row * HE + F + lane] = y;             // append channel block
    }
}

// ---------------- logits = (adj @ h_ext) @ Wout, then row mask ------------------
__global__ void final_k(const int* __restrict__ deg, const unsigned short* __restrict__ nbr,
                        const float* __restrict__ he, const float* __restrict__ Wout,
                        const void* __restrict__ mask, const int* __restrict__ flag,
                        float* __restrict__ out) {
    __shared__ float s[HE];
    int row  = blockIdx.x;
    int lane = threadIdx.x;                      // block = 64
    int d = deg[row];
    const unsigned short* nb = nbr + (size_t)row * NBS;
    if (lane < HE) {
        float acc = 0.f;
        for (int it = 0; it < d; ++it)
            acc += he[(int)nb[it] * HE + lane];
        s[lane] = acc;
    }
    __syncthreads();
    if (lane < 7) {
        float acc = 0.f;
        #pragma unroll
        for (int k = 0; k < HE; ++k) acc += s[k] * Wout[k * 7 + lane];
        int fl = *flag;
        bool mk;
        if (fl == 2)      mk = ((const float*)mask)[row] != 0.0f;
        else if (fl == 1) mk = ((const unsigned char*)mask)[row] != 0;
        else              mk = ((const int*)mask)[row] != 0;
        out[row * 7 + lane] = mk ? acc : 0.0f;
    }
}

extern "C" void kernel_launch(void* const* d_in, const int* in_sizes, int n_in,
                              void* d_out, int out_size, void* d_ws, size_t ws_size,
                              hipStream_t stream) {
    const float* x    = (const float*)d_in[0];
    const float* adj  = (const float*)d_in[1];
    const float* W0   = (const float*)d_in[2];
    const float* W1a  = (const float*)d_in[3];
    const float* W1b  = (const float*)d_in[4];
    const float* W2a  = (const float*)d_in[5];
    const float* W2b  = (const float*)d_in[6];
    const float* Wout = (const float*)d_in[7];
    const float* g1 = (const float*)d_in[8];
    const float* b1 = (const float*)d_in[9];
    const float* m1 = (const float*)d_in[10];
    const float* v1 = (const float*)d_in[11];
    const float* g2 = (const float*)d_in[12];
    const float* b2 = (const float*)d_in[13];
    const float* m2 = (const float*)d_in[14];
    const float* v2 = (const float*)d_in[15];
    const void*  mask = d_in[16];

    char* ws = (char*)d_ws;
    int*            flag = (int*)(ws + 0);
    int*            deg  = (int*)(ws + 256);                        //   6400 B
    unsigned short* nbr  = (unsigned short*)(ws + 8192);            // 307200 B
    float*          h0   = (float*)(ws + 8192 + 307200);            // 204800 B
    float*          he   = (float*)(ws + 8192 + 307200 + 204800);   // 307200 B

    float* out = (float*)d_out;

    detect_mask_k<<<1, 64, 0, stream>>>((const unsigned char*)mask, flag);
    build_csr_k<<<NN, 64, 0, stream>>>(adj, deg, nbr);
    gemm_xw0_k<<<NN, 256, 0, stream>>>(x, W0, h0);
    spmv32_k<<<NN, 64, 0, stream>>>(deg, nbr, h0, he);
    lgconv_k<32, 20><<<NN, 64, 0, stream>>>(deg, nbr, W1a, W1b, g1, b1, m1, v1, he);
    lgconv_k<40, 24><<<NN, 64, 0, stream>>>(deg, nbr, W2a, W2b, g2, b2, m2, v2, he);
    final_k<<<NN, 64, 0, stream>>>(deg, nbr, he, Wout, mask, flag, out);
}

// Round 2
// 93.770 us; speedup vs baseline: 1.1590x; 1.1590x over previous
//
#include <hip/hip_runtime.h>
#include <hip/hip_bf16.h>

// LGCN on MI355X. N=1600, Fin=1433, GCN hidden=32, two LGConv blocks (+8 ch each),
// out 7 channels, row mask. adj is dense binary [1600,1600], avg degree ~16.

constexpr int NN   = 1600;
constexpr int FIN  = 1433;
constexpr int HGCN = 32;
constexpr int HE   = 48;    // h_ext row stride (32 + 8 + 8)
constexpr int NBS  = 96;    // CSR neighbor stride
constexpr float BN_EPS = 1e-3f;

// ---------------- CSR build (float4 + ballot compaction) + mask detect --------
// grid = NN+1; block row==NN does the mask-layout detection (bool could be
// int32 / uint8 / f32 on device; detect from byte pattern).
__global__ void build_csr_k(const float* __restrict__ adj, int* __restrict__ deg,
                            unsigned short* __restrict__ nbr,
                            const unsigned char* __restrict__ mb, int* __restrict__ flag) {
    int row  = blockIdx.x;
    int lane = threadIdx.x;                      // block = 64 (one wave)

    if (row == NN) {                             // mask layout detection
        bool odd = false, flt = false;
        for (int i = lane; i < NN; i += 64) {    // first 1600 bytes safe in all layouts
            unsigned char b = mb[i];
            if (b) {
                int r = i & 3;
                if (r != 0) odd = true;
                if (r >= 2 && (b == 0x3F || b == 0x80)) flt = true;  // 1.0f = 00 00 80 3F
            }
        }
        unsigned long long mo = __ballot(odd);
        unsigned long long mf = __ballot(flt);
        if (lane == 0) *flag = mf ? 2 : (mo ? 1 : 0);  // 2=f32, 1=u8, 0=i32
        return;
    }

    const float*  ar  = adj + (size_t)row * NN;
    const float4* ar4 = (const float4*)ar;       // row*6400 B, 16B-aligned
    unsigned short* nb = nbr + (size_t)row * NBS;
    int cnt = 0;
    #pragma unroll
    for (int it = 0; it < 6; ++it) {             // 6*256 = 1536 elements
        float4 v = ar4[it * 64 + lane];
        int base = it * 256 + 4 * lane;
        #pragma unroll
        for (int c = 0; c < 4; ++c) {
            float vc = (c == 0) ? v.x : (c == 1) ? v.y : (c == 2) ? v.z : v.w;
            bool p = (vc != 0.0f);
            unsigned long long m = __ballot(p);
            if (p) {
                int off = cnt + __popcll(m & ((1ull << lane) - 1ull));
                if (off < NBS) nb[off] = (unsigned short)(base + c);
            }
            cnt += __popcll(m);
        }
    }
    {                                            // tail 64 elements
        float v = ar[1536 + lane];
        bool p = (v != 0.0f);
        unsigned long long m = __ballot(p);
        if (p) {
            int off = cnt + __popcll(m & ((1ull << lane) - 1ull));
            if (off < NBS) nb[off] = (unsigned short)(1536 + lane);
        }
        cnt += __popcll(m);
    }
    if (lane == 0) deg[row] = cnt < NBS ? cnt : NBS;
}

// ---------------- h0 = x @ W0   [1600,1433]@[1433,32] ---------------------------
// 8 rows/block staged to LDS via coalesced float4 (rows are contiguous: flat
// 45.9 KB span, 16B-aligned since 8*1433*4 % 16 == 0). 512 threads: 2-way
// split-K, thread = (ks, r, col). W0 (183 KB) stays L1/L2-resident.
constexpr int TMR = 8;
__global__ __launch_bounds__(512) void gemm_xw0_k(const float* __restrict__ x,
                                                  const float* __restrict__ W0,
                                                  float* __restrict__ h0) {
    __shared__ float sx[TMR * FIN];              // 45,856 B
    __shared__ float psum[2][TMR][HGCN];
    int t = threadIdx.x;
    const float4* src = (const float4*)(x + (size_t)blockIdx.x * TMR * FIN);
    float4* dst = (float4*)sx;
    constexpr int N4 = TMR * FIN / 4;            // 2866
    for (int i = t; i < N4; i += 512) dst[i] = src[i];
    __syncthreads();

    int col = t & 31;
    int r   = (t >> 5) & 7;
    int ks  = t >> 8;                            // 0 or 1
    int k0  = ks ? 717 : 0;
    int k1  = ks ? FIN : 717;
    const float* xr = sx + r * FIN;
    float acc = 0.f;
    #pragma unroll 4
    for (int k = k0; k < k1; ++k)
        acc += xr[k] * W0[k * HGCN + col];
    psum[ks][r][col] = acc;
    __syncthreads();
    if (t < 256)
        h0[(blockIdx.x * TMR + r) * HGCN + col] = psum[0][r][col] + psum[1][r][col];
}

// ---------------- h_ext[:,0:32] = adj @ h0 (CSR, adj values exactly 1.0) --------
__global__ void spmv32_k(const int* __restrict__ deg, const unsigned short* __restrict__ nbr,
                         const float* __restrict__ h0, float* __restrict__ he) {
    int row = blockIdx.x * 2 + (threadIdx.x >> 5);   // 2 rows per 64-thread block
    int f   = threadIdx.x & 31;
    int d = deg[row];
    const unsigned short* nb = nbr + (size_t)row * NBS;
    float acc = 0.f;
    for (int it = 0; it < d; ++it)
        acc += h0[(int)nb[it] * HGCN + f];
    he[row * HE + f] = acc;
}

// ---------------- fused topk(K=8) + conv1d(5) + conv1d(5) + BN ------------------
// top_k over adj[i,:]*h[:,f]: non-neighbor entries are exact 0.0, so result =
// up to 8 largest POSITIVE neighbor values (desc), zero-padded. Branchless bubble.
template<int F, int MID>
__global__ void lgconv_k(const int* __restrict__ deg, const unsigned short* __restrict__ nbr,
                         const float* __restrict__ Wa, const float* __restrict__ Wb,
                         const float* __restrict__ g,  const float* __restrict__ bb,
                         const float* __restrict__ mm, const float* __restrict__ vv,
                         float* __restrict__ he) {
    __shared__ float T[9][F];
    __shared__ float C1[5][MID];
    __shared__ float sWa[5 * F * MID];
    int row  = blockIdx.x;
    int lane = threadIdx.x;                      // block = 64 (one wave)

    {                                            // float4 weight staging (count % 4 == 0)
        const float4* w4 = (const float4*)Wa;
        float4*       s4 = (float4*)sWa;
        for (int i = lane; i < 5 * F * MID / 4; i += 64) s4[i] = w4[i];
    }

    int d = deg[row];
    const unsigned short* nb = nbr + (size_t)row * NBS;

    if (lane < F) {
        float t0=0.f,t1=0.f,t2=0.f,t3=0.f,t4=0.f,t5=0.f,t6=0.f,t7=0.f;
        for (int it = 0; it < d; ++it) {
            float val = he[(int)nb[it] * HE + lane];
            float c;
            c = t0; t0 = fmaxf(c, val); val = fminf(c, val);
            c = t1; t1 = fmaxf(c, val); val = fminf(c, val);
            c = t2; t2 = fmaxf(c, val); val = fminf(c, val);
            c = t3; t3 = fmaxf(c, val); val = fminf(c, val);
            c = t4; t4 = fmaxf(c, val); val = fminf(c, val);
            c = t5; t5 = fmaxf(c, val); val = fminf(c, val);
            c = t6; t6 = fmaxf(c, val); val = fminf(c, val);
            c = t7; t7 = fmaxf(c, val); val = fminf(c, val);
        }
        T[0][lane] = he[row * HE + lane];        // own feature first
        T[1][lane] = t0; T[2][lane] = t1; T[3][lane] = t2; T[4][lane] = t3;
        T[5][lane] = t4; T[6][lane] = t5; T[7][lane] = t6; T[8][lane] = t7;
    }
    __syncthreads();

    // conv1: out[p,o] = sum_{kw,ci} T[p+kw][ci] * Wa[kw,ci,o]
    for (int oi = lane; oi < 5 * MID; oi += 64) {
        int p = oi / MID, o = oi - p * MID;
        float acc = 0.f;
        #pragma unroll
        for (int kw = 0; kw < 5; ++kw) {
            const float* w  = &sWa[kw * F * MID + o];
            const float* tt = &T[p + kw][0];
            for (int ci = 0; ci < F; ++ci)
                acc += tt[ci] * w[ci * MID];
        }
        C1[p][o] = acc;
    }
    __syncthreads();

    // conv2 (only position 0 survives VALID) + batchnorm
    if (lane < 8) {
        float acc = 0.f;
        #pragma unroll
        for (int kw = 0; kw < 5; ++kw)
            for (int ci = 0; ci < MID; ++ci)
                acc += C1[kw][ci] * Wb[(kw * MID + ci) * 8 + lane];
        float y = g[lane] * (acc - mm[lane]) * rsqrtf(vv[lane] + BN_EPS) + bb[lane];
        he[row * HE + F + lane] = y;
    }
}

// ---------------- logits = (adj @ h_ext) @ Wout, then row mask ------------------
__global__ void final_k(const int* __restrict__ deg, const unsigned short* __restrict__ nbr,
                        const float* __restrict__ he, const float* __restrict__ Wout,
                        const void* __restrict__ mask, const int* __restrict__ flag,
                        float* __restrict__ out) {
    __shared__ float s[HE];
    int row  = blockIdx.x;
    int lane = threadIdx.x;                      // block = 64
    int d = deg[row];
    const unsigned short* nb = nbr + (size_t)row * NBS;
    if (lane < HE) {
        float acc = 0.f;
        for (int it = 0; it < d; ++it)
            acc += he[(int)nb[it] * HE + lane];
        s[lane] = acc;
    }
    __syncthreads();
    if (lane < 7) {
        float acc = 0.f;
        #pragma unroll
        for (int k = 0; k < HE; ++k) acc += s[k] * Wout[k * 7 + lane];
        int fl = *flag;
        bool mk;
        if (fl == 2)      mk = ((const float*)mask)[row] != 0.0f;
        else if (fl == 1) mk = ((const unsigned char*)mask)[row] != 0;
        else              mk = ((const int*)mask)[row] != 0;
        out[row * 7 + lane] = mk ? acc : 0.0f;
    }
}

extern "C" void kernel_launch(void* const* d_in, const int* in_sizes, int n_in,
                              void* d_out, int out_size, void* d_ws, size_t ws_size,
                              hipStream_t stream) {
    const float* x    = (const float*)d_in[0];
    const float* adj  = (const float*)d_in[1];
    const float* W0   = (const float*)d_in[2];
    const float* W1a  = (const float*)d_in[3];
    const float* W1b  = (const float*)d_in[4];
    const float* W2a  = (const float*)d_in[5];
    const float* W2b  = (const float*)d_in[6];
    const float* Wout = (const float*)d_in[7];
    const float* g1 = (const float*)d_in[8];
    const float* b1 = (const float*)d_in[9];
    const float* m1 = (const float*)d_in[10];
    const float* v1 = (const float*)d_in[11];
    const float* g2 = (const float*)d_in[12];
    const float* b2 = (const float*)d_in[13];
    const float* m2 = (const float*)d_in[14];
    const float* v2 = (const float*)d_in[15];
    const void*  mask = d_in[16];

    char* ws = (char*)d_ws;
    int*            flag = (int*)(ws + 0);
    int*            deg  = (int*)(ws + 256);                        //   6400 B
    unsigned short* nbr  = (unsigned short*)(ws + 8192);            // 307200 B
    float*          h0   = (float*)(ws + 8192 + 307200);            // 204800 B
    float*          he   = (float*)(ws + 8192 + 307200 + 204800);   // 307200 B

    float* out = (float*)d_out;

    build_csr_k<<<NN + 1, 64, 0, stream>>>(adj, deg, nbr, (const unsigned char*)mask, flag);
    gemm_xw0_k<<<NN / TMR, 512, 0, stream>>>(x, W0, h0);
    spmv32_k<<<NN / 2, 64, 0, stream>>>(deg, nbr, h0, he);
    lgconv_k<32, 20><<<NN, 64, 0, stream>>>(deg, nbr, W1a, W1b, g1, b1, m1, v1, he);
    lgconv_k<40, 24><<<NN, 64, 0, stream>>>(deg, nbr, W2a, W2b, g2, b2, m2, v2, he);
    final_k<<<NN, 64, 0, stream>>>(deg, nbr, he, Wout, mask, flag, out);
}

// Round 3
// 84.265 us; speedup vs baseline: 1.2897x; 1.1128x over previous
//
#include <hip/hip_runtime.h>
#include <hip/hip_bf16.h>

// LGCN on MI355X. N=1600, Fin=1433, GCN hidden=32, two LGConv blocks (+8 ch each),
// out 7 channels, row mask. adj is dense binary [1600,1600], avg degree ~16.

constexpr int NN   = 1600;
constexpr int FIN  = 1433;
constexpr int HGCN = 32;
constexpr int HE   = 48;    // h_ext row stride (32 + 8 + 8)
constexpr int NBS  = 96;    // CSR neighbor stride
constexpr float BN_EPS = 1e-3f;

// ---------------- CSR build (float4 + ballot compaction) + mask detect --------
__global__ void build_csr_k(const float* __restrict__ adj, int* __restrict__ deg,
                            unsigned short* __restrict__ nbr,
                            const unsigned char* __restrict__ mb, int* __restrict__ flag) {
    int row  = blockIdx.x;
    int lane = threadIdx.x;                      // block = 64 (one wave)

    if (row == NN) {                             // mask layout detection
        bool odd = false, flt = false;
        for (int i = lane; i < NN; i += 64) {    // first 1600 bytes safe in all layouts
            unsigned char b = mb[i];
            if (b) {
                int r = i & 3;
                if (r != 0) odd = true;
                if (r >= 2 && (b == 0x3F || b == 0x80)) flt = true;  // 1.0f = 00 00 80 3F
            }
        }
        unsigned long long mo = __ballot(odd);
        unsigned long long mf = __ballot(flt);
        if (lane == 0) *flag = mf ? 2 : (mo ? 1 : 0);  // 2=f32, 1=u8, 0=i32
        return;
    }

    const float*  ar  = adj + (size_t)row * NN;
    const float4* ar4 = (const float4*)ar;
    unsigned short* nb = nbr + (size_t)row * NBS;
    int cnt = 0;
    #pragma unroll
    for (int it = 0; it < 6; ++it) {             // 6*256 = 1536 elements
        float4 v = ar4[it * 64 + lane];
        int base = it * 256 + 4 * lane;
        #pragma unroll
        for (int c = 0; c < 4; ++c) {
            float vc = (c == 0) ? v.x : (c == 1) ? v.y : (c == 2) ? v.z : v.w;
            bool p = (vc != 0.0f);
            unsigned long long m = __ballot(p);
            if (p) {
                int off = cnt + __popcll(m & ((1ull << lane) - 1ull));
                if (off < NBS) nb[off] = (unsigned short)(base + c);
            }
            cnt += __popcll(m);
        }
    }
    {                                            // tail 64 elements
        float v = ar[1536 + lane];
        bool p = (v != 0.0f);
        unsigned long long m = __ballot(p);
        if (p) {
            int off = cnt + __popcll(m & ((1ull << lane) - 1ull));
            if (off < NBS) nb[off] = (unsigned short)(1536 + lane);
        }
        cnt += __popcll(m);
    }
    if (lane == 0) deg[row] = cnt < NBS ? cnt : NBS;
}

// ---------------- h0 = x @ W0, tiled + 16-way split-K ---------------------------
// grid = (50 row-blocks, 16 k-chunks), block 256. BM=32 rows, chunk=90 K.
// LDS: sx[32][92] (padded for float4 alignment) + sw[90][32] = 23.3 KB.
// Thread t: col=t&31, rq=t>>5; computes rows {rq, rq+8, rq+16, rq+24}.
constexpr int KS    = 16;
constexpr int CHUNK = 90;    // 16*90 = 1440 >= 1433 (last chunk 83 valid, zero-padded)
constexpr int BM    = 32;
constexpr int SXS   = 92;    // sx row stride (92*4 % 16 == 0 -> aligned float4 rows)

__global__ __launch_bounds__(256) void gemm_xw0_k(const float* __restrict__ x,
                                                  const float* __restrict__ W0,
                                                  float* __restrict__ hp) {
    __shared__ float sx[BM][SXS];
    __shared__ float sw[CHUNK * HGCN];
    int t    = threadIdx.x;
    int lane = t & 31;
    int rb   = blockIdx.x;
    int ks   = blockIdx.y;
    int row0 = rb * BM;
    int k0   = ks * CHUNK;
    int vk   = FIN - k0; if (vk > CHUNK) vk = CHUNK;   // valid k in this chunk

    // stage x rows (coalesced 128B runs, zero-pad tail)
    {
        int g = t >> 5;
        #pragma unroll
        for (int j = 0; j < 4; ++j) {
            int r = g + 8 * j;
            const float* xr = x + (size_t)(row0 + r) * FIN + k0;
            #pragma unroll
            for (int m = 0; m < 3; ++m) {
                int k = lane + 32 * m;
                if (k < CHUNK) sx[r][k] = (k < vk) ? xr[k] : 0.0f;
            }
        }
    }
    // stage W0 chunk (contiguous, 16B-aligned: k0*128 bytes)
    {
        const float4* w4  = (const float4*)(W0 + (size_t)k0 * HGCN);
        float4*       sw4 = (float4*)sw;
        int vf4 = vk * 8;                         // valid float4s (<= 720)
        for (int i = t; i < CHUNK * 8; i += 256)
            sw4[i] = (i < vf4) ? w4[i] : make_float4(0.f, 0.f, 0.f, 0.f);
    }
    __syncthreads();

    int col = lane;
    int rq  = t >> 5;
    float acc0 = 0.f, acc1 = 0.f, acc2 = 0.f, acc3 = 0.f;
    #pragma unroll 4
    for (int kk = 0; kk < 88; kk += 4) {
        float4 a0 = *(const float4*)&sx[rq     ][kk];
        float4 a1 = *(const float4*)&sx[rq +  8][kk];
        float4 a2 = *(const float4*)&sx[rq + 16][kk];
        float4 a3 = *(const float4*)&sx[rq + 24][kk];
        float w0v = sw[(kk + 0) * HGCN + col];
        float w1v = sw[(kk + 1) * HGCN + col];
        float w2v = sw[(kk + 2) * HGCN + col];
        float w3v = sw[(kk + 3) * HGCN + col];
        acc0 += a0.x * w0v + a0.y * w1v + a0.z * w2v + a0.w * w3v;
        acc1 += a1.x * w0v + a1.y * w1v + a1.z * w2v + a1.w * w3v;
        acc2 += a2.x * w0v + a2.y * w1v + a2.z * w2v + a2.w * w3v;
        acc3 += a3.x * w0v + a3.y * w1v + a3.z * w2v + a3.w * w3v;
    }
    #pragma unroll
    for (int kk = 88; kk < CHUNK; ++kk) {         // tail (90 % 4 == 2)
        float wv = sw[kk * HGCN + col];
        acc0 += sx[rq     ][kk] * wv;
        acc1 += sx[rq +  8][kk] * wv;
        acc2 += sx[rq + 16][kk] * wv;
        acc3 += sx[rq + 24][kk] * wv;
    }

    float* o = hp + (size_t)ks * NN * HGCN + (size_t)(row0 + rq) * HGCN + col;
    o[0 * 8 * HGCN] = acc0;
    o[1 * 8 * HGCN] = acc1;
    o[2 * 8 * HGCN] = acc2;
    o[3 * 8 * HGCN] = acc3;
}

// ---------------- h0 = sum over 16 split-K partials (deterministic order) ------
__global__ void reduce_k(const float* __restrict__ hp, float* __restrict__ h0) {
    int i = blockIdx.x * 128 + threadIdx.x;       // 400 blocks * 128 = 51200
    float s = 0.f;
    #pragma unroll
    for (int ks = 0; ks < KS; ++ks) s += hp[(size_t)ks * NN * HGCN + i];
    h0[i] = s;
}

// ---------------- h_ext[:,0:32] = adj @ h0 (CSR, adj values exactly 1.0) --------
__global__ void spmv32_k(const int* __restrict__ deg, const unsigned short* __restrict__ nbr,
                         const float* __restrict__ h0, float* __restrict__ he) {
    int row = blockIdx.x * 2 + (threadIdx.x >> 5);   // 2 rows per 64-thread block
    int f   = threadIdx.x & 31;
    int d = deg[row];
    const unsigned short* nb = nbr + (size_t)row * NBS;
    float acc = 0.f;
    for (int it = 0; it < d; ++it)
        acc += h0[(int)nb[it] * HGCN + f];
    he[row * HE + f] = acc;
}

// ---------------- fused topk(K=8) + conv1d(5) + conv1d(5) + BN ------------------
// top_k over adj[i,:]*h[:,f]: non-neighbor entries are exact 0.0, so result =
// up to 8 largest POSITIVE neighbor values (desc), zero-padded. Branchless bubble.
template<int F, int MID>
__global__ void lgconv_k(const int* __restrict__ deg, const unsigned short* __restrict__ nbr,
                         const float* __restrict__ Wa, const float* __restrict__ Wb,
                         const float* __restrict__ g,  const float* __restrict__ bb,
                         const float* __restrict__ mm, const float* __restrict__ vv,
                         float* __restrict__ he) {
    __shared__ float T[9][F];
    __shared__ float C1[5][MID];
    __shared__ float sWa[5 * F * MID];
    int row  = blockIdx.x;
    int lane = threadIdx.x;                      // block = 64 (one wave)

    {                                            // float4 weight staging
        const float4* w4 = (const float4*)Wa;
        float4*       s4 = (float4*)sWa;
        for (int i = lane; i < 5 * F * MID / 4; i += 64) s4[i] = w4[i];
    }

    int d = deg[row];
    const unsigned short* nb = nbr + (size_t)row * NBS;

    if (lane < F) {
        float t0=0.f,t1=0.f,t2=0.f,t3=0.f,t4=0.f,t5=0.f,t6=0.f,t7=0.f;
        for (int it = 0; it < d; ++it) {
            float val = he[(int)nb[it] * HE + lane];
            float c;
            c = t0; t0 = fmaxf(c, val); val = fminf(c, val);
            c = t1; t1 = fmaxf(c, val); val = fminf(c, val);
            c = t2; t2 = fmaxf(c, val); val = fminf(c, val);
            c = t3; t3 = fmaxf(c, val); val = fminf(c, val);
            c = t4; t4 = fmaxf(c, val); val = fminf(c, val);
            c = t5; t5 = fmaxf(c, val); val = fminf(c, val);
            c = t6; t6 = fmaxf(c, val); val = fminf(c, val);
            c = t7; t7 = fmaxf(c, val); val = fminf(c, val);
        }
        T[0][lane] = he[row * HE + lane];        // own feature first
        T[1][lane] = t0; T[2][lane] = t1; T[3][lane] = t2; T[4][lane] = t3;
        T[5][lane] = t4; T[6][lane] = t5; T[7][lane] = t6; T[8][lane] = t7;
    }
    __syncthreads();

    // conv1: out[p,o] = sum_{kw,ci} T[p+kw][ci] * Wa[kw,ci,o]
    for (int oi = lane; oi < 5 * MID; oi += 64) {
        int p = oi / MID, o = oi - p * MID;
        float acc = 0.f;
        #pragma unroll
        for (int kw = 0; kw < 5; ++kw) {
            const float* w  = &sWa[kw * F * MID + o];
            const float* tt = &T[p + kw][0];
            for (int ci = 0; ci < F; ++ci)
                acc += tt[ci] * w[ci * MID];
        }
        C1[p][o] = acc;
    }
    __syncthreads();

    // conv2 (only position 0 survives VALID) + batchnorm
    if (lane < 8) {
        float acc = 0.f;
        #pragma unroll
        for (int kw = 0; kw < 5; ++kw)
            for (int ci = 0; ci < MID; ++ci)
                acc += C1[kw][ci] * Wb[(kw * MID + ci) * 8 + lane];
        float y = g[lane] * (acc - mm[lane]) * rsqrtf(vv[lane] + BN_EPS) + bb[lane];
        he[row * HE + F + lane] = y;
    }
}

// ---------------- logits = (adj @ h_ext) @ Wout, then row mask ------------------
__global__ void final_k(const int* __restrict__ deg, const unsigned short* __restrict__ nbr,
                        const float* __restrict__ he, const float* __restrict__ Wout,
                        const void* __restrict__ mask, const int* __restrict__ flag,
                        float* __restrict__ out) {
    __shared__ float s[HE];
    int row  = blockIdx.x;
    int lane = threadIdx.x;                      // block = 64
    int d = deg[row];
    const unsigned short* nb = nbr + (size_t)row * NBS;
    if (lane < HE) {
        float acc = 0.f;
        for (int it = 0; it < d; ++it)
            acc += he[(int)nb[it] * HE + lane];
        s[lane] = acc;
    }
    __syncthreads();
    if (lane < 7) {
        float acc = 0.f;
        #pragma unroll
        for (int k = 0; k < HE; ++k) acc += s[k] * Wout[k * 7 + lane];
        int fl = *flag;
        bool mk;
        if (fl == 2)      mk = ((const float*)mask)[row] != 0.0f;
        else if (fl == 1) mk = ((const unsigned char*)mask)[row] != 0;
        else              mk = ((const int*)mask)[row] != 0;
        out[row * 7 + lane] = mk ? acc : 0.0f;
    }
}

extern "C" void kernel_launch(void* const* d_in, const int* in_sizes, int n_in,
                              void* d_out, int out_size, void* d_ws, size_t ws_size,
                              hipStream_t stream) {
    const float* x    = (const float*)d_in[0];
    const float* adj  = (const float*)d_in[1];
    const float* W0   = (const float*)d_in[2];
    const float* W1a  = (const float*)d_in[3];
    const float* W1b  = (const float*)d_in[4];
    const float* W2a  = (const float*)d_in[5];
    const float* W2b  = (const float*)d_in[6];
    const float* Wout = (const float*)d_in[7];
    const float* g1 = (const float*)d_in[8];
    const float* b1 = (const float*)d_in[9];
    const float* m1 = (const float*)d_in[10];
    const float* v1 = (const float*)d_in[11];
    const float* g2 = (const float*)d_in[12];
    const float* b2 = (const float*)d_in[13];
    const float* m2 = (const float*)d_in[14];
    const float* v2 = (const float*)d_in[15];
    const void*  mask = d_in[16];

    char* ws = (char*)d_ws;
    int*            flag = (int*)(ws + 0);
    int*            deg  = (int*)(ws + 256);                        //   6400 B
    unsigned short* nbr  = (unsigned short*)(ws + 8192);            // 307200 B
    float*          h0   = (float*)(ws + 8192 + 307200);            // 204800 B
    float*          he   = (float*)(ws + 520192);                   // 307200 B
    float*          hp   = (float*)(ws + 827392);                   // 16*204800 = 3.3 MB

    float* out = (float*)d_out;

    build_csr_k<<<NN + 1, 64, 0, stream>>>(adj, deg, nbr, (const unsigned char*)mask, flag);
    gemm_xw0_k<<<dim3(NN / BM, KS), 256, 0, stream>>>(x, W0, hp);
    reduce_k<<<NN * HGCN / 128, 128, 0, stream>>>(hp, h0);
    spmv32_k<<<NN / 2, 64, 0, stream>>>(deg, nbr, h0, he);
    lgconv_k<32, 20><<<NN, 64, 0, stream>>>(deg, nbr, W1a, W1b, g1, b1, m1, v1, he);
    lgconv_k<40, 24><<<NN, 64, 0, stream>>>(deg, nbr, W2a, W2b, g2, b2, m2, v2, he);
    final_k<<<NN, 64, 0, stream>>>(deg, nbr, he, Wout, mask, flag, out);
}